// Round 1
// baseline (1093.667 us; speedup 1.0000x reference)
//
#include <hip/hip_runtime.h>
#include <math.h>

#define NANCH 16128      // 64*64*3 + 32*32*3 + 16*16*3
#define N0    12288
#define N1    3072
#define NB    16
#define NDET  100
#define SCORE_TH 0.25f
#define IOU_TH   0.5f
#define IMGSZ    512.0f

#define NMS_THREADS 1024
#define SLOTS 16         // ceil(16128/1024)

__device__ __constant__ float c_anchors[18] = {
    12.f,16.f, 19.f,36.f, 40.f,28.f,
    36.f,75.f, 76.f,55.f, 72.f,146.f,
    142.f,110.f, 192.f,243.f, 459.f,401.f
};

__device__ __forceinline__ float sigmoidf_(float x) {
    return 1.0f / (1.0f + expf(-x));
}

__global__ void decode_kernel(const float* __restrict__ p0,
                              const float* __restrict__ p1,
                              const float* __restrict__ p2,
                              float4* __restrict__ boxes,
                              float* __restrict__ scores,
                              float* __restrict__ classes) {
    int t = blockIdx.x * blockDim.x + threadIdx.x;
    if (t >= NB * NANCH) return;
    int b = t / NANCH;
    int n = t - b * NANCH;

    const float* base;
    int S, local, scale;
    float stride;
    if (n < N0)            { scale = 0; base = p0; S = 64; stride = 8.f;  local = n; }
    else if (n < N0 + N1)  { scale = 1; base = p1; S = 32; stride = 16.f; local = n - N0; }
    else                   { scale = 2; base = p2; S = 16; stride = 32.f; local = n - N0 - N1; }

    const float* p = base + ((size_t)b * S * S * 3 + local) * 85;

    int a    = local % 3;
    int cell = local / 3;
    int gj   = cell % S;   // grid x
    int gi   = cell / S;   // grid y

    float tx = p[0], ty = p[1], tw = p[2], th = p[3], tobj = p[4];

    // class argmax on raw logits (sigmoid is monotone); first-occurrence tie-break
    float bestl = p[5];
    int   bc    = 0;
    #pragma unroll 8
    for (int c = 1; c < 80; ++c) {
        float v = p[5 + c];
        if (v > bestl) { bestl = v; bc = c; }
    }

    // mirror reference op order: ((sig*2 - 0.5) + grid) * stride
    float bx = ((sigmoidf_(tx) * 2.0f - 0.5f) + (float)gj) * stride;
    float by = ((sigmoidf_(ty) * 2.0f - 0.5f) + (float)gi) * stride;
    float sw = sigmoidf_(tw) * 2.0f; sw = sw * sw;
    float sh = sigmoidf_(th) * 2.0f; sh = sh * sh;
    // wh * (anchors/stride) * stride == wh * anchors bit-exactly (stride = 2^k)
    float aw = c_anchors[scale * 6 + a * 2];
    float ah = c_anchors[scale * 6 + a * 2 + 1];
    float bw = sw * aw;
    float bh = sh * ah;

    bx = fminf(fmaxf(bx, 0.f), IMGSZ);
    by = fminf(fmaxf(by, 0.f), IMGSZ);
    bw = fminf(fmaxf(bw, 0.f), IMGSZ);
    bh = fminf(fmaxf(bh, 0.f), IMGSZ);

    float score = sigmoidf_(tobj) * sigmoidf_(bestl);
    score = (score >= SCORE_TH) ? score : -1.0f;

    boxes[t]   = make_float4(bx, by, bw, bh);
    scores[t]  = score;
    classes[t] = (float)bc;
}

__global__ __launch_bounds__(NMS_THREADS)
void nms_kernel(const float4* __restrict__ boxes,
                const float*  __restrict__ scores,
                const float*  __restrict__ classes,
                float* __restrict__ out) {
    int b   = blockIdx.x;
    int tid = threadIdx.x;
    int lane = tid & 63;
    int wave = tid >> 6;

    const float4* bb = boxes  + (size_t)b * NANCH;
    const float*  ss = scores + (size_t)b * NANCH;
    float* o = out + (size_t)b * NDET * 6;

    __shared__ float red_v[16];
    __shared__ int   red_i[16];
    __shared__ float bcast[4];

    // register-resident scores + boxes: thread t owns contiguous [t*16, t*16+16)
    float  sc[SLOTS];
    float4 bx[SLOTS];
    int base = tid * SLOTS;
    #pragma unroll
    for (int k = 0; k < SLOTS; ++k) {
        int g = base + k;
        if (g < NANCH) { sc[k] = ss[g]; bx[k] = bb[g]; }
        else           { sc[k] = -1.0f; bx[k] = make_float4(0.f, 0.f, 0.f, 0.f); }
    }

    for (int it = 0; it < NDET; ++it) {
        // --- local argmax (static indices; first-occurrence via strict >) ---
        float v  = -2.0f;
        int   vi = 0x7fffffff;
        #pragma unroll
        for (int k = 0; k < SLOTS; ++k) {
            if (sc[k] > v) { v = sc[k]; vi = base + k; }
        }
        // --- wave reduce (64 lanes), lexicographic (max v, min idx) ---
        #pragma unroll
        for (int off = 32; off; off >>= 1) {
            float ov = __shfl_xor(v, off);
            int   oi = __shfl_xor(vi, off);
            if (ov > v || (ov == v && oi < vi)) { v = ov; vi = oi; }
        }
        if (lane == 0) { red_v[wave] = v; red_i[wave] = vi; }
        __syncthreads();                               // barrier 1
        if (wave == 0) {
            float v2 = (lane < 16) ? red_v[lane] : -2.0f;
            int   i2 = (lane < 16) ? red_i[lane] : 0x7fffffff;
            #pragma unroll
            for (int off = 8; off; off >>= 1) {
                float ov = __shfl_xor(v2, off);
                int   oi = __shfl_xor(i2, off);
                if (ov > v2 || (ov == v2 && oi < i2)) { v2 = ov; i2 = oi; }
            }
            if (lane == 0) { red_v[0] = v2; red_i[0] = i2; }
        }
        __syncthreads();                               // barrier 2
        float bestV = red_v[0];
        int   bestI = red_i[0];

        if (bestV <= 0.0f) {
            // all remaining detections are zeros; cooperative fill and exit
            for (int z = it * 6 + tid; z < NDET * 6; z += NMS_THREADS) o[z] = 0.0f;
            return;
        }

        // owner broadcasts best box through LDS (static register indices)
        #pragma unroll
        for (int k = 0; k < SLOTS; ++k) {
            if (base + k == bestI) {
                bcast[0] = bx[k].x; bcast[1] = bx[k].y;
                bcast[2] = bx[k].z; bcast[3] = bx[k].w;
            }
        }
        __syncthreads();                               // barrier 3
        float Bx = bcast[0], By = bcast[1], Bw = bcast[2], Bh = bcast[3];

        if (tid == 0) {
            o[it * 6 + 0] = Bx;
            o[it * 6 + 1] = By;
            o[it * 6 + 2] = Bw;
            o[it * 6 + 3] = Bh;
            o[it * 6 + 4] = bestV;
            o[it * 6 + 5] = classes[(size_t)b * NANCH + bestI];
        }

        // --- suppress: DIoU(best, each owned box) > 0.5 -> score = -1 ---
        float b1minx = Bx - Bw * 0.5f, b1maxx = Bx + Bw * 0.5f;
        float b1miny = By - Bh * 0.5f, b1maxy = By + Bh * 0.5f;
        float area1  = Bw * Bh;
        #pragma unroll
        for (int k = 0; k < SLOTS; ++k) {
            float4 c = bx[k];
            float b2minx = c.x - c.z * 0.5f, b2maxx = c.x + c.z * 0.5f;
            float b2miny = c.y - c.w * 0.5f, b2maxy = c.y + c.w * 0.5f;
            float iw = fmaxf(fminf(b1maxx, b2maxx) - fmaxf(b1minx, b2minx), 0.f);
            float ih = fmaxf(fminf(b1maxy, b2maxy) - fmaxf(b1miny, b2miny), 0.f);
            float inter = iw * ih;
            float uni   = area1 + c.z * c.w - inter;
            float iou   = inter / (uni + 1e-9f);
            float ex = fmaxf(b1maxx, b2maxx) - fminf(b1minx, b2minx);
            float ey = fmaxf(b1maxy, b2maxy) - fminf(b1miny, b2miny);
            float c2 = ex * ex + ey * ey + 1e-9f;
            float dx = Bx - c.x, dy = By - c.y;
            float diou = iou - (dx * dx + dy * dy) / c2;
            if (diou > IOU_TH) sc[k] = -1.0f;
            if (base + k == bestI) sc[k] = -1.0f;   // explicit .at[i].set(-1)
        }
        // no trailing barrier needed: red/bcast writes in the next iteration
        // are separated from this iteration's reads by barriers 1-3.
    }
}

extern "C" void kernel_launch(void* const* d_in, const int* in_sizes, int n_in,
                              void* d_out, int out_size, void* d_ws, size_t ws_size,
                              hipStream_t stream) {
    const float* p0 = (const float*)d_in[0];
    const float* p1 = (const float*)d_in[1];
    const float* p2 = (const float*)d_in[2];
    float* out = (float*)d_out;

    char* ws = (char*)d_ws;
    float4* boxes  = (float4*)ws;                                   // 16*16128*16 B
    float*  scores = (float*)(ws + (size_t)NB * NANCH * sizeof(float4));
    float*  classes = scores + (size_t)NB * NANCH;                  // total ~6.2 MB

    int total = NB * NANCH;
    decode_kernel<<<(total + 255) / 256, 256, 0, stream>>>(p0, p1, p2, boxes, scores, classes);
    nms_kernel<<<NB, NMS_THREADS, 0, stream>>>(boxes, scores, classes, out);
}